// Round 1
// baseline (1500.425 us; speedup 1.0000x reference)
//
#include <hip/hip_runtime.h>
#include <hip/hip_bf16.h>

// Problem constants (from reference)
#define N_NODES 50000
#define N_EDGES 800000
#define IN_F    128
#define OUT_F   256

// ---------------------------------------------------------------------------
// Kernel 1: edge-parallel scatter SpMM.
//   agg[row[e], :] += val[e] * x[col[e], :]
// 32 lanes per edge; each lane handles 4 consecutive features (float4 load,
// 4 scalar atomicAdds). Consecutive lanes -> consecutive addresses: coalesced.
// ---------------------------------------------------------------------------
__global__ __launch_bounds__(256)
void spmm_scatter(const float* __restrict__ x,
                  const int*   __restrict__ row,
                  const int*   __restrict__ col,
                  const float* __restrict__ val,
                  float*       __restrict__ agg,
                  int n_edges) {
    int t = blockIdx.x * blockDim.x + threadIdx.x;
    int e = t >> 5;                 // 32 threads per edge
    if (e >= n_edges) return;
    int lane = t & 31;              // feature group: lane*4 .. lane*4+3

    int r = row[e];
    int c = col[e];
    float v = val[e];

    const float4 xv = *reinterpret_cast<const float4*>(
        x + (size_t)c * IN_F + lane * 4);
    float* a = agg + (size_t)r * IN_F + lane * 4;
    atomicAdd(a + 0, v * xv.x);
    atomicAdd(a + 1, v * xv.y);
    atomicAdd(a + 2, v * xv.z);
    atomicAdd(a + 3, v * xv.w);
}

// ---------------------------------------------------------------------------
// Kernel 2: out = agg @ W + b   (M=50000, K=128, N=256), fp32 vector ALU.
// Each block: 8 rows x 256 cols. agg rows staged in LDS (reads are
// wave-uniform broadcasts -> no bank conflicts). Each thread owns one
// output column; weight column read from global (128 KB, L2-resident).
// ---------------------------------------------------------------------------
#define ROWS_PER_BLOCK 8

__global__ __launch_bounds__(256)
void gemm_bias(const float* __restrict__ agg,
               const float* __restrict__ W,    // [IN_F, OUT_F]
               const float* __restrict__ bias,
               float*       __restrict__ out,
               int M) {
    __shared__ float sA[ROWS_PER_BLOCK * IN_F];   // 4 KB

    const int block_row = blockIdx.x * ROWS_PER_BLOCK;
    const int tid = threadIdx.x;

    // Stage 8 rows x 128 feats = 1024 floats = 256 float4 with 256 threads.
    {
        const float4 av = *reinterpret_cast<const float4*>(
            agg + (size_t)block_row * IN_F + (size_t)tid * 4);
        reinterpret_cast<float4*>(sA)[tid] = av;
    }
    __syncthreads();

    const int f = tid;  // output column 0..255
    float acc[ROWS_PER_BLOCK];
#pragma unroll
    for (int r = 0; r < ROWS_PER_BLOCK; ++r) acc[r] = 0.f;

#pragma unroll 8
    for (int k = 0; k < IN_F; ++k) {
        const float w = W[(size_t)k * OUT_F + f];
#pragma unroll
        for (int r = 0; r < ROWS_PER_BLOCK; ++r)
            acc[r] += sA[r * IN_F + k] * w;
    }

    const float bv = bias[f];
#pragma unroll
    for (int r = 0; r < ROWS_PER_BLOCK; ++r) {
        int m = block_row + r;
        if (m < M)
            out[(size_t)m * OUT_F + f] = acc[r] + bv;
    }
}

// ---------------------------------------------------------------------------
extern "C" void kernel_launch(void* const* d_in, const int* in_sizes, int n_in,
                              void* d_out, int out_size, void* d_ws, size_t ws_size,
                              hipStream_t stream) {
    const float* x        = (const float*)d_in[0];   // [N_NODES, IN_F]
    const int*   edge_row = (const int*)  d_in[1];   // [N_EDGES]
    const int*   edge_col = (const int*)  d_in[2];   // [N_EDGES]
    const float* edge_val = (const float*)d_in[3];   // [N_EDGES]
    const float* weight   = (const float*)d_in[4];   // [IN_F, OUT_F]
    const float* bias     = (const float*)d_in[5];   // [OUT_F]
    float* out = (float*)d_out;                      // [N_NODES, OUT_F]

    float* agg = (float*)d_ws;                       // [N_NODES, IN_F]
    const size_t agg_bytes = (size_t)N_NODES * IN_F * sizeof(float);

    // ws is re-poisoned 0xAA before every timed launch -> zero it ourselves.
    hipMemsetAsync(agg, 0, agg_bytes, stream);

    // Scatter: 32 threads/edge -> 8 edges per 256-thread block.
    {
        const long long threads = (long long)N_EDGES * 32;
        const int block = 256;
        const int grid = (int)((threads + block - 1) / block);
        spmm_scatter<<<grid, block, 0, stream>>>(x, edge_row, edge_col,
                                                 edge_val, agg, N_EDGES);
    }

    // GEMM + bias: 50000/8 = 6250 blocks.
    {
        const int block = 256;
        const int grid = (N_NODES + ROWS_PER_BLOCK - 1) / ROWS_PER_BLOCK;
        gemm_bias<<<grid, block, 0, stream>>>(agg, weight, bias, out, N_NODES);
    }
}

// Round 2
// 349.442 us; speedup vs baseline: 4.2938x; 4.2938x over previous
//
#include <hip/hip_runtime.h>
#include <hip/hip_bf16.h>

// Problem constants (from reference)
#define N_NODES 50000
#define N_EDGES 800000
#define IN_F    128
#define OUT_F   256

// ---------------------------------------------------------------------------
// CSR build (device-side, every launch):
//   1) histogram of edge rows           (int atomics, 800k)
//   2) exclusive scan of counts (3 kernels: block scan, top scan, add)
//   3) fill sorted (col,val) arrays     (int atomics, 800k)
// Then one fused kernel: gather-SpMM (CSR rows -> registers -> LDS) + GEMM.
// No fp32 atomics anywhere.
// ---------------------------------------------------------------------------

__global__ __launch_bounds__(256)
void edge_histogram(const int* __restrict__ row, int* __restrict__ cnt, int E) {
    int e = blockIdx.x * blockDim.x + threadIdx.x;
    if (e < E) atomicAdd(&cnt[row[e]], 1);
}

#define SCAN_BLK 1024

__global__ __launch_bounds__(SCAN_BLK)
void scan_block(const int* __restrict__ cnt, int* __restrict__ rptr,
                int* __restrict__ bsum, int n) {
    __shared__ int s[SCAN_BLK];
    const int gid = blockIdx.x * SCAN_BLK + threadIdx.x;
    const int v = (gid < n) ? cnt[gid] : 0;
    s[threadIdx.x] = v;
    __syncthreads();
    // Hillis-Steele inclusive scan
    for (int d = 1; d < SCAN_BLK; d <<= 1) {
        int t = (threadIdx.x >= d) ? s[threadIdx.x - d] : 0;
        __syncthreads();
        s[threadIdx.x] += t;
        __syncthreads();
    }
    const int incl = s[threadIdx.x];
    if (gid < n) rptr[gid] = incl - v;            // exclusive within block
    if (threadIdx.x == SCAN_BLK - 1) bsum[blockIdx.x] = incl;
}

__global__ __launch_bounds__(64)
void scan_top(int* __restrict__ bsum, int nb) {   // nb <= 64, one wave
    const int lane = threadIdx.x;
    int v = (lane < nb) ? bsum[lane] : 0;
    for (int d = 1; d < 64; d <<= 1) {
        int u = __shfl_up(v, d);
        if (lane >= d) v += u;
    }
    int ex = __shfl_up(v, 1);
    if (lane == 0) ex = 0;
    if (lane < nb) bsum[lane] = ex;
}

__global__ __launch_bounds__(SCAN_BLK)
void scan_add(int* __restrict__ rptr, const int* __restrict__ bsum, int n) {
    const int gid = blockIdx.x * SCAN_BLK + threadIdx.x;
    if (gid < n) rptr[gid] += bsum[blockIdx.x];
}

__global__ __launch_bounds__(256)
void edge_fill(const int* __restrict__ row, const int* __restrict__ col,
               const float* __restrict__ val,
               const int* __restrict__ rptr, int* __restrict__ fillc,
               int* __restrict__ colsS, float* __restrict__ valsS, int E) {
    int e = blockIdx.x * blockDim.x + threadIdx.x;
    if (e >= E) return;
    const int r = row[e];
    const int p = rptr[r] + atomicAdd(&fillc[r], 1);
    colsS[p] = col[e];
    valsS[p] = val[e];
}

// ---------------------------------------------------------------------------
// Fused gather-SpMM + GEMM + bias.
// Block = 256 threads (4 waves), NB = 8 nodes/block.
// Phase 1: wave w gathers nodes (base+w) and (base+w+4). Each lane owns 2
//          features (float2). Edge (col,val) loaded coalesced per 64-chunk,
//          broadcast via __shfl. Result rows -> LDS.
// Phase 2: classic [8 x 128] @ [128 x 256] from LDS; thread owns one out col.
// ---------------------------------------------------------------------------
#define NB 8

__global__ __launch_bounds__(256)
void gcn_fused(const float* __restrict__ x,
               const int*   __restrict__ rptr,
               const int*   __restrict__ cnt,
               const int*   __restrict__ colsS,
               const float* __restrict__ valsS,
               const float* __restrict__ W,     // [IN_F, OUT_F]
               const float* __restrict__ bias,  // [OUT_F]
               float*       __restrict__ out,   // [M, OUT_F]
               int M) {
    __shared__ float sA[NB][IN_F];   // 4 KB

    const int tid  = threadIdx.x;
    const int wave = tid >> 6;
    const int lane = tid & 63;
    const int base = blockIdx.x * NB;

    // ---- Phase 1: gather ----
    for (int s = 0; s < 2; ++s) {
        const int nl   = wave + s * 4;
        const int node = base + nl;
        float2 acc = make_float2(0.f, 0.f);
        if (node < M) {
            const int st = rptr[node];
            const int n  = cnt[node];
            for (int j0 = 0; j0 < n; j0 += 64) {
                const int nj = min(64, n - j0);
                int   c_l = 0;
                float v_l = 0.f;
                if (lane < nj) {
                    c_l = colsS[st + j0 + lane];
                    v_l = valsS[st + j0 + lane];
                }
                for (int j = 0; j < nj; ++j) {
                    const int   c = __shfl(c_l, j);
                    const float v = __shfl(v_l, j);
                    const float2 xv = *reinterpret_cast<const float2*>(
                        x + (size_t)c * IN_F + lane * 2);
                    acc.x += v * xv.x;
                    acc.y += v * xv.y;
                }
            }
        }
        *reinterpret_cast<float2*>(&sA[nl][lane * 2]) = acc;
    }
    __syncthreads();

    // ---- Phase 2: GEMM + bias ----
    const int f = tid;   // output column 0..255
    float acc[NB];
#pragma unroll
    for (int r = 0; r < NB; ++r) acc[r] = 0.f;

#pragma unroll 8
    for (int k = 0; k < IN_F; ++k) {
        const float w = W[(size_t)k * OUT_F + f];
#pragma unroll
        for (int r = 0; r < NB; ++r)
            acc[r] += sA[r][k] * w;
    }

    const float bv = bias[f];
#pragma unroll
    for (int r = 0; r < NB; ++r) {
        const int m = base + r;
        if (m < M)
            out[(size_t)m * OUT_F + f] = acc[r] + bv;
    }
}

// ---------------------------------------------------------------------------
extern "C" void kernel_launch(void* const* d_in, const int* in_sizes, int n_in,
                              void* d_out, int out_size, void* d_ws, size_t ws_size,
                              hipStream_t stream) {
    const float* x        = (const float*)d_in[0];   // [N_NODES, IN_F]
    const int*   edge_row = (const int*)  d_in[1];   // [N_EDGES]
    const int*   edge_col = (const int*)  d_in[2];   // [N_EDGES]
    const float* edge_val = (const float*)d_in[3];   // [N_EDGES]
    const float* weight   = (const float*)d_in[4];   // [IN_F, OUT_F]
    const float* bias     = (const float*)d_in[5];   // [OUT_F]
    float* out = (float*)d_out;                      // [N_NODES, OUT_F]

    // Workspace layout (ints):
    //   cnt[50000] | rptr[50000] | fillc[50000] | bsum[64] | colsS[800000] | valsS[800000]
    int* ws_i   = (int*)d_ws;
    int* cnt    = ws_i;
    int* rptr   = ws_i + 50000;
    int* fillc  = ws_i + 100000;
    int* bsum   = ws_i + 150000;
    int* colsS  = ws_i + 150064;
    float* valsS = (float*)(ws_i + 950064);
    // total: 1,750,064 ints = 7.0 MB

    // Zero cnt/fillc (and rptr/bsum, harmless) — ws is re-poisoned each launch.
    hipMemsetAsync(ws_i, 0, (size_t)150064 * sizeof(int), stream);

    const int nscan = (N_NODES + SCAN_BLK - 1) / SCAN_BLK;   // 49

    edge_histogram<<<(N_EDGES + 255) / 256, 256, 0, stream>>>(edge_row, cnt, N_EDGES);
    scan_block<<<nscan, SCAN_BLK, 0, stream>>>(cnt, rptr, bsum, N_NODES);
    scan_top<<<1, 64, 0, stream>>>(bsum, nscan);
    scan_add<<<nscan, SCAN_BLK, 0, stream>>>(rptr, bsum, N_NODES);
    edge_fill<<<(N_EDGES + 255) / 256, 256, 0, stream>>>(
        edge_row, edge_col, edge_val, rptr, fillc, colsS, valsS, N_EDGES);

    gcn_fused<<<(N_NODES + NB - 1) / NB, 256, 0, stream>>>(
        x, rptr, cnt, colsS, valsS, weight, bias, out, N_NODES);
}

// Round 3
// 249.926 us; speedup vs baseline: 6.0035x; 1.3982x over previous
//
#include <hip/hip_runtime.h>

// Problem constants (from reference)
#define N_NODES 50000
#define N_EDGES 800000
#define IN_F    128
#define OUT_F   256

// ---------------------------------------------------------------------------
// CSR build (every launch; inputs are restored and ws re-poisoned each call):
//   1) hist_rank: cnt histogram + per-edge rank (one atomic pass total)
//   2) exclusive scan of cnt -> rptr (3 small kernels)
//   3) edge_fill: recs[rptr[row]+rank] = packed (val,col) 8-byte record
// Then: gather_agg (1 wave/node, 8 edges x 8 lanes) writes agg into the
// FIRST 128 floats of each 256-float output row (in-place), then gemm_bias
// expands each row 128 -> 256 with W staged in LDS.
// No fp32 atomics anywhere.
// ---------------------------------------------------------------------------

__global__ __launch_bounds__(256)
void hist_rank(const int* __restrict__ row, int* __restrict__ cnt,
               int* __restrict__ rank, int E) {
    int e = blockIdx.x * blockDim.x + threadIdx.x;
    if (e < E) rank[e] = atomicAdd(&cnt[row[e]], 1);
}

#define SCAN_BLK 1024

__global__ __launch_bounds__(SCAN_BLK)
void scan_block(const int* __restrict__ cnt, int* __restrict__ rptr,
                int* __restrict__ bsum, int n) {
    __shared__ int s[SCAN_BLK];
    const int gid = blockIdx.x * SCAN_BLK + threadIdx.x;
    const int v = (gid < n) ? cnt[gid] : 0;
    s[threadIdx.x] = v;
    __syncthreads();
    for (int d = 1; d < SCAN_BLK; d <<= 1) {
        int t = (threadIdx.x >= d) ? s[threadIdx.x - d] : 0;
        __syncthreads();
        s[threadIdx.x] += t;
        __syncthreads();
    }
    const int incl = s[threadIdx.x];
    if (gid < n) rptr[gid] = incl - v;            // exclusive within block
    if (threadIdx.x == SCAN_BLK - 1) bsum[blockIdx.x] = incl;
}

__global__ __launch_bounds__(64)
void scan_top(int* __restrict__ bsum, int nb) {   // nb <= 64, one wave
    const int lane = threadIdx.x;
    int v = (lane < nb) ? bsum[lane] : 0;
    for (int d = 1; d < 64; d <<= 1) {
        int u = __shfl_up(v, d);
        if (lane >= d) v += u;
    }
    int ex = __shfl_up(v, 1);
    if (lane == 0) ex = 0;
    if (lane < nb) bsum[lane] = ex;
}

__global__ __launch_bounds__(SCAN_BLK)
void scan_add(int* __restrict__ rptr, const int* __restrict__ bsum, int n) {
    const int gid = blockIdx.x * SCAN_BLK + threadIdx.x;
    if (gid < n) rptr[gid] += bsum[blockIdx.x];
}

__global__ __launch_bounds__(256)
void edge_fill(const int* __restrict__ row, const int* __restrict__ col,
               const float* __restrict__ val,
               const int* __restrict__ rptr, const int* __restrict__ rank,
               unsigned long long* __restrict__ recs, int E) {
    int e = blockIdx.x * blockDim.x + threadIdx.x;
    if (e >= E) return;
    const int r = row[e];
    const int p = rptr[r] + rank[e];
    const unsigned long long rec =
        ((unsigned long long)__float_as_uint(val[e]) << 32) | (unsigned)col[e];
    recs[p] = rec;
}

// ---------------------------------------------------------------------------
// Gather: one wave per node. lane = es*8 + fg:
//   es = lane>>3 : edge slot (8 edges processed in parallel per round)
//   fg = lane&7  : feature group (16 consecutive feats = 4x float4)
// Tree-reduce over es via __shfl_xor, es==0 lanes store to out[node][0:128].
// ---------------------------------------------------------------------------
__global__ __launch_bounds__(256)
void gather_agg(const float* __restrict__ x,
                const int*   __restrict__ rptr,
                const int*   __restrict__ cnt,
                const unsigned long long* __restrict__ recs,
                float*       __restrict__ out,   // [M, OUT_F]; cols 0..127 used
                int M) {
    const int wave = threadIdx.x >> 6;
    const int lane = threadIdx.x & 63;
    const int node = blockIdx.x * 4 + wave;
    if (node >= M) return;

    const int es = lane >> 3;
    const int fg = lane & 7;

    const int st = rptr[node];
    const int d  = cnt[node];

    float acc[16];
#pragma unroll
    for (int i = 0; i < 16; ++i) acc[i] = 0.f;

    for (int j0 = 0; j0 < d; j0 += 8) {
        const int  idx = j0 + es;
        const bool ok  = (idx < d);
        const unsigned long long rec = recs[st + (ok ? idx : 0)];
        const int   c = (int)(unsigned)(rec & 0xffffffffull);
        const float v = ok ? __uint_as_float((unsigned)(rec >> 32)) : 0.f;

        const float4* xp = reinterpret_cast<const float4*>(
            x + (size_t)c * IN_F + fg * 16);
        const float4 x0 = xp[0], x1 = xp[1], x2 = xp[2], x3 = xp[3];

        acc[0]  += v * x0.x; acc[1]  += v * x0.y; acc[2]  += v * x0.z; acc[3]  += v * x0.w;
        acc[4]  += v * x1.x; acc[5]  += v * x1.y; acc[6]  += v * x1.z; acc[7]  += v * x1.w;
        acc[8]  += v * x2.x; acc[9]  += v * x2.y; acc[10] += v * x2.z; acc[11] += v * x2.w;
        acc[12] += v * x3.x; acc[13] += v * x3.y; acc[14] += v * x3.z; acc[15] += v * x3.w;
    }

    // Reduce across the 8 edge slots (lanes differing in bits 3..5).
#pragma unroll
    for (int i = 0; i < 16; ++i) {
        acc[i] += __shfl_xor(acc[i], 8);
        acc[i] += __shfl_xor(acc[i], 16);
        acc[i] += __shfl_xor(acc[i], 32);
    }

    if (es == 0) {
        float* op = out + (size_t)node * OUT_F + fg * 16;
        reinterpret_cast<float4*>(op)[0] = make_float4(acc[0],  acc[1],  acc[2],  acc[3]);
        reinterpret_cast<float4*>(op)[1] = make_float4(acc[4],  acc[5],  acc[6],  acc[7]);
        reinterpret_cast<float4*>(op)[2] = make_float4(acc[8],  acc[9],  acc[10], acc[11]);
        reinterpret_cast<float4*>(op)[3] = make_float4(acc[12], acc[13], acc[14], acc[15]);
    }
}

// ---------------------------------------------------------------------------
// GEMM + bias, in-place row expansion 128 -> 256.
// Block: 32 rows x 256 cols, 256 threads. agg rows staged to LDS first
// (so overwriting cols 0..127 afterwards is race-free; blocks only touch
// their own rows). W staged in LDS in 32-row chunks (200 MB total L2 traffic).
// Thread tile: 8 rows x 4 cols.
// ---------------------------------------------------------------------------
#define GM 32
#define KC 32

__global__ __launch_bounds__(256)
void gemm_bias(const float* __restrict__ W,     // [IN_F, OUT_F]
               const float* __restrict__ bias,  // [OUT_F]
               float*       __restrict__ out,   // [M, OUT_F]
               int M) {
    __shared__ float sA[GM][IN_F];    // 16 KB
    __shared__ float sW[KC][OUT_F];   // 32 KB

    const int tid = threadIdx.x;
    const int r0  = blockIdx.x * GM;

    // Stage 32 rows x 128 feats from out[r][0:128] (written by gather_agg).
#pragma unroll
    for (int i = 0; i < 4; ++i) {
        const int fi = tid + i * 256;       // float4 index 0..1023
        const int r  = fi >> 5;
        const int q  = fi & 31;
        const int gr = r0 + r;
        const float4 v = (gr < M)
            ? *reinterpret_cast<const float4*>(out + (size_t)gr * OUT_F + q * 4)
            : make_float4(0.f, 0.f, 0.f, 0.f);
        *reinterpret_cast<float4*>(&sA[r][q * 4]) = v;
    }

    const int c4 = tid & 63;   // col group: cols c4*4 .. c4*4+3
    const int ty = tid >> 6;   // row group: rows ty*8 .. ty*8+7

    float acc[8][4];
#pragma unroll
    for (int i = 0; i < 8; ++i)
#pragma unroll
        for (int j = 0; j < 4; ++j) acc[i][j] = 0.f;

    for (int k0 = 0; k0 < IN_F; k0 += KC) {
        // Stage W[k0..k0+31][0:256] -> sW  (2048 float4, 8 per thread).
#pragma unroll
        for (int i = 0; i < 8; ++i) {
            const int fi = tid + i * 256;   // 0..2047
            const int kk = fi >> 6;
            const int c  = fi & 63;
            *reinterpret_cast<float4*>(&sW[kk][c * 4]) =
                *reinterpret_cast<const float4*>(W + (size_t)(k0 + kk) * OUT_F + c * 4);
        }
        __syncthreads();   // covers sA on first iteration too

#pragma unroll 8
        for (int kk = 0; kk < KC; ++kk) {
            const float4 w = *reinterpret_cast<const float4*>(&sW[kk][c4 * 4]);
#pragma unroll
            for (int i = 0; i < 8; ++i) {
                const float a = sA[ty * 8 + i][k0 + kk];
                acc[i][0] += a * w.x;
                acc[i][1] += a * w.y;
                acc[i][2] += a * w.z;
                acc[i][3] += a * w.w;
            }
        }
        __syncthreads();
    }

    const float4 bv = *reinterpret_cast<const float4*>(bias + c4 * 4);
#pragma unroll
    for (int i = 0; i < 8; ++i) {
        const int gr = r0 + ty * 8 + i;
        if (gr < M) {
            const float4 o = make_float4(acc[i][0] + bv.x, acc[i][1] + bv.y,
                                         acc[i][2] + bv.z, acc[i][3] + bv.w);
            *reinterpret_cast<float4*>(out + (size_t)gr * OUT_F + c4 * 4) = o;
        }
    }
}

// ---------------------------------------------------------------------------
extern "C" void kernel_launch(void* const* d_in, const int* in_sizes, int n_in,
                              void* d_out, int out_size, void* d_ws, size_t ws_size,
                              hipStream_t stream) {
    const float* x        = (const float*)d_in[0];   // [N_NODES, IN_F]
    const int*   edge_row = (const int*)  d_in[1];   // [N_EDGES]
    const int*   edge_col = (const int*)  d_in[2];   // [N_EDGES]
    const float* edge_val = (const float*)d_in[3];   // [N_EDGES]
    const float* weight   = (const float*)d_in[4];   // [IN_F, OUT_F]
    const float* bias     = (const float*)d_in[5];   // [OUT_F]
    float* out = (float*)d_out;                      // [N_NODES, OUT_F]

    // Workspace (ints): cnt[50000] rptr[50000] bsum[64] rank[800000] recs[2*800000]
    // total = 2,500,064 ints = 10.0 MB (well under the 25.6 MB proven in round 1)
    int* cnt  = (int*)d_ws;
    int* rptr = cnt + 50000;
    int* bsum = rptr + 50000;
    int* rank = bsum + 64;
    unsigned long long* recs = (unsigned long long*)(rank + 800000);  // 8B-aligned

    // Only cnt needs zeroing (ws is re-poisoned 0xAA before every launch).
    hipMemsetAsync(cnt, 0, (size_t)N_NODES * sizeof(int), stream);

    const int nscan = (N_NODES + SCAN_BLK - 1) / SCAN_BLK;   // 49

    hist_rank<<<(N_EDGES + 255) / 256, 256, 0, stream>>>(edge_row, cnt, rank, N_EDGES);
    scan_block<<<nscan, SCAN_BLK, 0, stream>>>(cnt, rptr, bsum, N_NODES);
    scan_top<<<1, 64, 0, stream>>>(bsum, nscan);
    scan_add<<<nscan, SCAN_BLK, 0, stream>>>(rptr, bsum, N_NODES);
    edge_fill<<<(N_EDGES + 255) / 256, 256, 0, stream>>>(
        edge_row, edge_col, edge_val, rptr, rank, recs, N_EDGES);

    gather_agg<<<(N_NODES + 3) / 4, 256, 0, stream>>>(
        x, rptr, cnt, recs, out, N_NODES);

    gemm_bias<<<(N_NODES + GM - 1) / GM, 256, 0, stream>>>(
        weight, bias, out, N_NODES);
}

// Round 5
// 219.441 us; speedup vs baseline: 6.8375x; 1.1389x over previous
//
#include <hip/hip_runtime.h>
#include <hip/hip_bf16.h>

// Problem constants (from reference)
#define N_NODES 50000
#define N_EDGES 800000
#define IN_F    128
#define OUT_F   256

typedef __attribute__((ext_vector_type(8))) short  short8;   // 8 bf16 (16B)
typedef __attribute__((ext_vector_type(4))) float  f32x4;    // MFMA acc

static __device__ __forceinline__ unsigned short f2bf(float f) {
    __hip_bfloat16 h = __float2bfloat16(f);   // RNE
    return *reinterpret_cast<unsigned short*>(&h);
}

// ---------------------------------------------------------------------------
// Pipeline:
//   convert_x : x fp32 -> xb bf16 (halves gather traffic)
//   convert_w : W [128][256] fp32 -> Wt [256][128] bf16 (K-contiguous for MFMA B)
//   CSR build : hist_rank -> 3-kernel scan -> edge_fill (packed 8B records)
//   gather    : 1 wave/node, 8 edges x 8 lanes, fp32 accum, bf16 agg stored
//               IN-PLACE into out[row][bytes 0..255]
//   gemm_mfma : bf16 MFMA 16x16x32, 64 rows x 256 cols per block, no LDS,
//               frags direct from L2; bias fused; expands rows in-place.
// No fp32 atomics anywhere.
// ---------------------------------------------------------------------------

__global__ __launch_bounds__(256)
void convert_x(const float* __restrict__ x, unsigned short* __restrict__ xb, int n8) {
    const int i = blockIdx.x * blockDim.x + threadIdx.x;   // 8 floats per thread
    if (i >= n8) return;
    const float4* xp = reinterpret_cast<const float4*>(x) + (size_t)i * 2;
    const float4 a = xp[0], b = xp[1];
    uint4 o;
    o.x = (unsigned)f2bf(a.x) | ((unsigned)f2bf(a.y) << 16);
    o.y = (unsigned)f2bf(a.z) | ((unsigned)f2bf(a.w) << 16);
    o.z = (unsigned)f2bf(b.x) | ((unsigned)f2bf(b.y) << 16);
    o.w = (unsigned)f2bf(b.z) | ((unsigned)f2bf(b.w) << 16);
    reinterpret_cast<uint4*>(xb)[i] = o;
}

// Wt[n][k] = bf16(W[k][n]).  Grid 16 blocks x 256 thr; thread -> (col, k-chunk).
__global__ __launch_bounds__(256)
void convert_w(const float* __restrict__ W, unsigned short* __restrict__ Wt) {
    const int n  = blockIdx.x * 16 + (threadIdx.x & 15);
    const int kc = threadIdx.x >> 4;            // 16 chunks of 8 k
    unsigned q[4];
#pragma unroll
    for (int j = 0; j < 4; ++j) {
        const int k = kc * 8 + j * 2;
        const unsigned short u0 = f2bf(W[(size_t)k * OUT_F + n]);
        const unsigned short u1 = f2bf(W[(size_t)(k + 1) * OUT_F + n]);
        q[j] = (unsigned)u0 | ((unsigned)u1 << 16);
    }
    *reinterpret_cast<uint4*>(Wt + (size_t)n * IN_F + kc * 8) =
        make_uint4(q[0], q[1], q[2], q[3]);
}

__global__ __launch_bounds__(256)
void hist_rank(const int* __restrict__ row, int* __restrict__ cnt,
               int* __restrict__ rank, int E) {
    int e = blockIdx.x * blockDim.x + threadIdx.x;
    if (e < E) rank[e] = atomicAdd(&cnt[row[e]], 1);
}

#define SCAN_BLK 1024

__global__ __launch_bounds__(SCAN_BLK)
void scan_block(const int* __restrict__ cnt, int* __restrict__ rptr,
                int* __restrict__ bsum, int n) {
    __shared__ int s[SCAN_BLK];
    const int gid = blockIdx.x * SCAN_BLK + threadIdx.x;
    const int v = (gid < n) ? cnt[gid] : 0;
    s[threadIdx.x] = v;
    __syncthreads();
    for (int d = 1; d < SCAN_BLK; d <<= 1) {
        int t = (threadIdx.x >= d) ? s[threadIdx.x - d] : 0;
        __syncthreads();
        s[threadIdx.x] += t;
        __syncthreads();
    }
    const int incl = s[threadIdx.x];
    if (gid < n) rptr[gid] = incl - v;
    if (threadIdx.x == SCAN_BLK - 1) bsum[blockIdx.x] = incl;
}

__global__ __launch_bounds__(64)
void scan_top(int* __restrict__ bsum, int nb) {
    const int lane = threadIdx.x;
    int v = (lane < nb) ? bsum[lane] : 0;
    for (int d = 1; d < 64; d <<= 1) {
        int u = __shfl_up(v, d);
        if (lane >= d) v += u;
    }
    int ex = __shfl_up(v, 1);
    if (lane == 0) ex = 0;
    if (lane < nb) bsum[lane] = ex;
}

__global__ __launch_bounds__(SCAN_BLK)
void scan_add(int* __restrict__ rptr, const int* __restrict__ bsum, int n) {
    const int gid = blockIdx.x * SCAN_BLK + threadIdx.x;
    if (gid < n) rptr[gid] += bsum[blockIdx.x];
}

__global__ __launch_bounds__(256)
void edge_fill(const int* __restrict__ row, const int* __restrict__ col,
               const float* __restrict__ val,
               const int* __restrict__ rptr, const int* __restrict__ rank,
               unsigned long long* __restrict__ recs, int E) {
    int e = blockIdx.x * blockDim.x + threadIdx.x;
    if (e >= E) return;
    const int r = row[e];
    const int p = rptr[r] + rank[e];
    const unsigned long long rec =
        ((unsigned long long)__float_as_uint(val[e]) << 32) | (unsigned)col[e];
    recs[p] = rec;
}

// ---------------------------------------------------------------------------
// Gather (bf16 x): wave/node; es = lane>>3 edge slot, fg = lane&7 feature
// group (16 feats = 2x uint4). fp32 accumulate, shfl_xor reduce over es,
// bf16 agg packed into out[node] bytes 0..255.
// ---------------------------------------------------------------------------
__global__ __launch_bounds__(256)
void gather_agg(const unsigned short* __restrict__ xb,
                const int* __restrict__ rptr,
                const int* __restrict__ cnt,
                const unsigned long long* __restrict__ recs,
                float* __restrict__ out, int M) {
    const int wave = threadIdx.x >> 6;
    const int lane = threadIdx.x & 63;
    const int node = blockIdx.x * 4 + wave;
    if (node >= M) return;

    const int es = lane >> 3;
    const int fg = lane & 7;

    const int st = rptr[node];
    const int d  = cnt[node];

    float acc[16];
#pragma unroll
    for (int i = 0; i < 16; ++i) acc[i] = 0.f;

    for (int j0 = 0; j0 < d; j0 += 8) {
        const int  idx = j0 + es;
        const bool ok  = (idx < d);
        const unsigned long long rec = recs[st + (ok ? idx : 0)];
        const int   c = (int)(unsigned)(rec & 0xffffffffull);
        const float v = ok ? __uint_as_float((unsigned)(rec >> 32)) : 0.f;

        const uint4* xp = reinterpret_cast<const uint4*>(
            xb + (size_t)c * IN_F + fg * 16);
        const uint4 a = xp[0], b = xp[1];
        const unsigned w[8] = {a.x, a.y, a.z, a.w, b.x, b.y, b.z, b.w};
#pragma unroll
        for (int j = 0; j < 8; ++j) {
            acc[2 * j]     += v * __uint_as_float(w[j] << 16);
            acc[2 * j + 1] += v * __uint_as_float(w[j] & 0xffff0000u);
        }
    }

#pragma unroll
    for (int i = 0; i < 16; ++i) {
        acc[i] += __shfl_xor(acc[i], 8);
        acc[i] += __shfl_xor(acc[i], 16);
        acc[i] += __shfl_xor(acc[i], 32);
    }

    if (es == 0) {
        unsigned q[8];
#pragma unroll
        for (int j = 0; j < 8; ++j)
            q[j] = (unsigned)f2bf(acc[2 * j]) | ((unsigned)f2bf(acc[2 * j + 1]) << 16);
        unsigned short* op =
            reinterpret_cast<unsigned short*>(out) + (size_t)node * 512 + fg * 16;
        reinterpret_cast<uint4*>(op)[0] = make_uint4(q[0], q[1], q[2], q[3]);
        reinterpret_cast<uint4*>(op)[1] = make_uint4(q[4], q[5], q[6], q[7]);
    }
}

// ---------------------------------------------------------------------------
// MFMA GEMM: out[r][c] = sum_k aggb[r][k] * Wt[c][k] + bias[c]
// Block 256 thr = 4 waves (wvm = wave>>1, wvn = wave&1); block = 64 rows x 256
// cols; wave = 32 rows x 128 cols = 2x8 tiles of 16x16, K = 4 steps of 32.
// A frags prefetched (its own rows), barrier, then B frags from Wt + MFMA.
// In-place safe: each block only reads/writes its own 64 rows; barrier keeps
// writes to cols 0..63 (bytes 0..255, the aggb region) after all A reads.
// ---------------------------------------------------------------------------
__global__ __launch_bounds__(256)
void gemm_mfma(const unsigned short* __restrict__ Wt,
               const float* __restrict__ bias,
               float* __restrict__ out, int M) {
    const int tid = threadIdx.x;
    const int wv  = tid >> 6;
    const int l   = tid & 63;
    const int wvm = wv >> 1, wvn = wv & 1;
    const int lr  = l & 15;          // A row-in-tile / B,C col-in-tile
    const int lg  = l >> 4;          // k-group / C row-group
    const int r0  = blockIdx.x * 64;

    // Prefetch A fragments: rows of THIS wave only, all 4 K-steps.
    short8 af[2][4];
#pragma unroll
    for (int mt = 0; mt < 2; ++mt) {
        const int row = r0 + wvm * 32 + mt * 16 + lr;
        const unsigned short* ap =
            reinterpret_cast<const unsigned short*>(out) + (size_t)row * 512;
#pragma unroll
        for (int kk = 0; kk < 4; ++kk) {
            short8 v = {0, 0, 0, 0, 0, 0, 0, 0};
            if (row < M)
                v = *reinterpret_cast<const short8*>(ap + kk * 32 + lg * 8);
            af[mt][kk] = v;
        }
    }
    __syncthreads();   // all aggb reads complete before any in-place writes

    f32x4 acc[2][8];
#pragma unroll
    for (int mt = 0; mt < 2; ++mt)
#pragma unroll
        for (int nt = 0; nt < 8; ++nt) acc[mt][nt] = (f32x4){0.f, 0.f, 0.f, 0.f};

#pragma unroll
    for (int kk = 0; kk < 4; ++kk) {
        short8 bf[8];
#pragma unroll
        for (int nt = 0; nt < 8; ++nt) {
            const int colc = wvn * 128 + nt * 16 + lr;
            bf[nt] = *reinterpret_cast<const short8*>(
                Wt + (size_t)colc * IN_F + kk * 32 + lg * 8);
        }
#pragma unroll
        for (int mt = 0; mt < 2; ++mt)
#pragma unroll
            for (int nt = 0; nt < 8; ++nt)
                acc[mt][nt] = __builtin_amdgcn_mfma_f32_16x16x32_bf16(
                    af[mt][kk], bf[nt], acc[mt][nt], 0, 0, 0);
    }

#pragma unroll
    for (int nt = 0; nt < 8; ++nt) {
        const int colc = wvn * 128 + nt * 16 + lr;
        const float bv = bias[colc];
#pragma unroll
        for (int mt = 0; mt < 2; ++mt) {
            const int rbase = r0 + wvm * 32 + mt * 16 + lg * 4;
#pragma unroll
            for (int r = 0; r < 4; ++r) {
                const int gr = rbase + r;
                if (gr < M)
                    out[(size_t)gr * OUT_F + colc] = acc[mt][nt][r] + bv;
            }
        }
    }
}

// ---------------------------------------------------------------------------
extern "C" void kernel_launch(void* const* d_in, const int* in_sizes, int n_in,
                              void* d_out, int out_size, void* d_ws, size_t ws_size,
                              hipStream_t stream) {
    const float* x        = (const float*)d_in[0];
    const int*   edge_row = (const int*)  d_in[1];
    const int*   edge_col = (const int*)  d_in[2];
    const float* edge_val = (const float*)d_in[3];
    const float* weight   = (const float*)d_in[4];
    const float* bias     = (const float*)d_in[5];
    float* out = (float*)d_out;

    // Workspace layout (bytes), total 22,865,792 B = 22.87 MB (< 25.6 MB
    // proven available in round 1):
    //   xb   @ 0          : 6,400,000 ushort = 12,800,000 B   (bf16 x)
    //   recs @ 12,800,000 :   800,000 u64    =  6,400,000 B
    //   Wt   @ 19,200,000 :    32,768 ushort =     65,536 B
    //   cnt  @ 19,265,536 :    50,000 int
    //   rptr              :    50,000 int
    //   bsum              :        64 int
    //   rank              :   800,000 int
    char* w = (char*)d_ws;
    unsigned short* xb = (unsigned short*)w;
    unsigned long long* recs = (unsigned long long*)(w + 12800000);
    unsigned short* Wt = (unsigned short*)(w + 19200000);
    int* cnt  = (int*)(w + 19265536);
    int* rptr = cnt + 50000;
    int* bsum = rptr + 50000;
    int* rank = bsum + 64;

    hipMemsetAsync(cnt, 0, (size_t)N_NODES * sizeof(int), stream);

    convert_x<<<(N_NODES * IN_F / 8 + 255) / 256, 256, 0, stream>>>(
        x, xb, N_NODES * IN_F / 8);
    convert_w<<<16, 256, 0, stream>>>(weight, Wt);

    const int nscan = (N_NODES + SCAN_BLK - 1) / SCAN_BLK;   // 49
    hist_rank<<<(N_EDGES + 255) / 256, 256, 0, stream>>>(edge_row, cnt, rank, N_EDGES);
    scan_block<<<nscan, SCAN_BLK, 0, stream>>>(cnt, rptr, bsum, N_NODES);
    scan_top<<<1, 64, 0, stream>>>(bsum, nscan);
    scan_add<<<nscan, SCAN_BLK, 0, stream>>>(rptr, bsum, N_NODES);
    edge_fill<<<(N_EDGES + 255) / 256, 256, 0, stream>>>(
        edge_row, edge_col, edge_val, rptr, rank, recs, N_EDGES);

    gather_agg<<<(N_NODES + 3) / 4, 256, 0, stream>>>(
        xb, rptr, cnt, recs, out, N_NODES);

    gemm_mfma<<<(N_NODES + 63) / 64, 256, 0, stream>>>(
        Wt, bias, out, N_NODES);
}